// Round 2
// baseline (2091.151 us; speedup 1.0000x reference)
//
#include <hip/hip_runtime.h>

#define B_ 128
#define T_ 1024
#define D_ 512
#define K_ 16

// ---------- cross-lane helpers (16-lane groups inside wave64; ds_swizzle works per-32-lane half) ----------
template<int I>
__device__ __forceinline__ float bcast16(float v) {
  // lane' = (lane & 0x10) | I  -> broadcast lane I of each 16-group
  return __int_as_float(__builtin_amdgcn_ds_swizzle(__float_as_int(v), (I << 5) | 0x10));
}
template<int M>
__device__ __forceinline__ float xshf16(float v) {
  return __int_as_float(__builtin_amdgcn_ds_swizzle(__float_as_int(v), (M << 10) | 0x1F));
}
template<int M>
__device__ __forceinline__ int xshf16i(int v) {
  return __builtin_amdgcn_ds_swizzle(v, (M << 10) | 0x1F);
}

#define ALLGATHER16(sv, p) do { \
  sv[0]=bcast16<0>(p);  sv[1]=bcast16<1>(p);  sv[2]=bcast16<2>(p);  sv[3]=bcast16<3>(p);  \
  sv[4]=bcast16<4>(p);  sv[5]=bcast16<5>(p);  sv[6]=bcast16<6>(p);  sv[7]=bcast16<7>(p);  \
  sv[8]=bcast16<8>(p);  sv[9]=bcast16<9>(p);  sv[10]=bcast16<10>(p); sv[11]=bcast16<11>(p); \
  sv[12]=bcast16<12>(p); sv[13]=bcast16<13>(p); sv[14]=bcast16<14>(p); sv[15]=bcast16<15>(p); \
} while (0)

#define SUM16(s) do { s += xshf16<1>(s); s += xshf16<2>(s); s += xshf16<4>(s); s += xshf16<8>(s); } while (0)

// ---------- mask -> lengths (handles byte-bool OR int32 mask storage; mask[0][0] is always true) ----------
__global__ void len_kernel(const void* __restrict__ maskp, int* __restrict__ lens) {
  const int b = blockIdx.x;
  const int l = threadIdx.x;
  const int isInt = (((const int*)maskp)[0] == 1);  // byte storage would read 0x01010101 here
  int cnt = 0;
  if (isInt) {
    const int* m = (const int*)maskp + b * T_;
    for (int t = l; t < T_; t += 64) cnt += (m[t] != 0);
  } else {
    const unsigned char* m = (const unsigned char*)maskp + b * T_;
    for (int t = l; t < T_; t += 64) cnt += (m[t] != 0);
  }
#pragma unroll
  for (int s = 1; s < 64; s <<= 1) cnt += __shfl_xor(cnt, s);
  if (l == 0) lens[b] = cnt;
}

// ---------- emissions: logits[b][t][k] = dot(H[b][t][:], W[k][:]) + bias[k], stored as emis[t][b][k] ----------
__global__ __launch_bounds__(256) void emis_kernel(const float* __restrict__ H,
                                                   const float* __restrict__ W,
                                                   const float* __restrict__ bias,
                                                   float* __restrict__ emis) {
  __shared__ float Wt[D_ * K_];  // [d][k], 32 KB; reads are wave-uniform -> broadcast, conflict-free
  for (int idx = threadIdx.x; idx < D_ * K_; idx += 256) {
    int k = idx >> 9;        // W is (K, D) row-major
    int d = idx & (D_ - 1);
    Wt[d * K_ + k] = W[idx];
  }
  __syncthreads();
  const int r = blockIdx.x * 256 + threadIdx.x;  // row into (B*T)
  const float4* hrow = (const float4*)(H + (size_t)r * D_);
  float acc[16];
#pragma unroll
  for (int k = 0; k < 16; ++k) acc[k] = bias[k];
  float4 a[8], an[8];
#pragma unroll
  for (int u = 0; u < 8; ++u) a[u] = hrow[u];
  for (int c = 0; c < 16; ++c) {          // 16 chunks of 32 dims
    if (c < 15) {
#pragma unroll
      for (int u = 0; u < 8; ++u) an[u] = hrow[(c + 1) * 8 + u];  // prefetch next chunk under FMAs
    }
#pragma unroll
    for (int u = 0; u < 8; ++u) {
#pragma unroll
      for (int q = 0; q < 4; ++q) {
        const int d = c * 32 + u * 4 + q;
        const float4* wr = (const float4*)(Wt + d * K_);
        float x = (q == 0) ? a[u].x : (q == 1) ? a[u].y : (q == 2) ? a[u].z : a[u].w;
        float4 w0 = wr[0], w1 = wr[1], w2 = wr[2], w3 = wr[3];
        acc[0]  = fmaf(x, w0.x, acc[0]);  acc[1]  = fmaf(x, w0.y, acc[1]);
        acc[2]  = fmaf(x, w0.z, acc[2]);  acc[3]  = fmaf(x, w0.w, acc[3]);
        acc[4]  = fmaf(x, w1.x, acc[4]);  acc[5]  = fmaf(x, w1.y, acc[5]);
        acc[6]  = fmaf(x, w1.z, acc[6]);  acc[7]  = fmaf(x, w1.w, acc[7]);
        acc[8]  = fmaf(x, w2.x, acc[8]);  acc[9]  = fmaf(x, w2.y, acc[9]);
        acc[10] = fmaf(x, w2.z, acc[10]); acc[11] = fmaf(x, w2.w, acc[11]);
        acc[12] = fmaf(x, w3.x, acc[12]); acc[13] = fmaf(x, w3.y, acc[13]);
        acc[14] = fmaf(x, w3.z, acc[14]); acc[15] = fmaf(x, w3.w, acc[15]);
      }
    }
#pragma unroll
    for (int u = 0; u < 8; ++u) a[u] = an[u];
  }
  const int b = r >> 10;          // T_ = 1024
  const int t = r & (T_ - 1);
  float4* o = (float4*)(emis + ((size_t)t * B_ + b) * K_);
  o[0] = make_float4(acc[0], acc[1], acc[2], acc[3]);
  o[1] = make_float4(acc[4], acc[5], acc[6], acc[7]);
  o[2] = make_float4(acc[8], acc[9], acc[10], acc[11]);
  o[3] = make_float4(acc[12], acc[13], acc[14], acc[15]);
}

// ---------- CRF: blocks 0-31 logZ, 32-63 viterbi fwd+backtrack (hist in LDS), 64-95 numerator ----------
// 64 thr = 1 wave = 4 batches x 16 states. Single-wave block -> no __syncthreads needed for LDS reuse.
__global__ __launch_bounds__(64) void crf_kernel(const float* __restrict__ emis,
                                                 const float* __restrict__ trans,
                                                 const float* __restrict__ start,
                                                 const float* __restrict__ endv,
                                                 const int* __restrict__ labels,
                                                 const int* __restrict__ lens,
                                                 float* __restrict__ logZ,
                                                 float* __restrict__ num,
                                                 float* __restrict__ out) {
  __shared__ unsigned char hist_lds[T_ * 64];  // [t][b4][j] = 64 KB (only role 1 touches it)
  const int role = blockIdx.x >> 5;
  const int blk  = blockIdx.x & 31;
  const int lane = threadIdx.x;
  const int j = lane & 15;
  const int b = blk * 4 + (lane >> 4);
  const int len = lens[b];

  if (role == 0) {
    // ---- logZ in probability domain; normalize every 8 steps; 8-deep emis prefetch ring ----
    float Tc[16];
#pragma unroll
    for (int i = 0; i < 16; ++i) Tc[i] = __expf(trans[i * K_ + j]);  // column j of exp(trans)
    float p = __expf(start[j] + emis[b * K_ + j]);                   // t=0
    float c = 0.0f;
    float er[8];
#pragma unroll
    for (int s = 0; s < 8; ++s) er[s] = emis[((1 + s) * B_ + b) * K_ + j];
    for (int tb = 1; tb < T_; tb += 8) {
#pragma unroll
      for (int s = 0; s < 8; ++s) {
        const int t = tb + s;
        if (t < T_) {
          float e = er[s];
          if (t + 8 < T_) er[s] = emis[((t + 8) * B_ + b) * K_ + j];  // refill ring, 8 in flight
          float sv[16];
          ALLGATHER16(sv, p);
          float qa = fmaf(sv[0],  Tc[0],  fmaf(sv[1],  Tc[1],  fmaf(sv[2],  Tc[2],  sv[3]  * Tc[3])));
          float qb = fmaf(sv[4],  Tc[4],  fmaf(sv[5],  Tc[5],  fmaf(sv[6],  Tc[6],  sv[7]  * Tc[7])));
          float qc = fmaf(sv[8],  Tc[8],  fmaf(sv[9],  Tc[9],  fmaf(sv[10], Tc[10], sv[11] * Tc[11])));
          float qd = fmaf(sv[12], Tc[12], fmaf(sv[13], Tc[13], fmaf(sv[14], Tc[14], sv[15] * Tc[15])));
          float q = ((qa + qb) + (qc + qd)) * __expf(e);
          p = (t < len) ? q : p;          // masked step keeps old state
          if ((t & 7) == 0) {             // growth <= e^2.8/step; 8 steps safe in f32
            float S = p;
            SUM16(S);
            c += __logf(S);
            p *= __fdividef(1.0f, S);
          }
        }
      }
    }
    float u = p * __expf(endv[j]);
    SUM16(u);
    if (j == 0) logZ[b] = c + __logf(u);

  } else if (role == 1) {
    // ---- Viterbi forward (max-plus), hist in LDS, then in-kernel backtrack ----
    float Tc[16];
#pragma unroll
    for (int i = 0; i < 16; ++i) Tc[i] = trans[i * K_ + j];
    float sc = start[j] + emis[b * K_ + j];
    float er[8];
#pragma unroll
    for (int s = 0; s < 8; ++s) er[s] = emis[((1 + s) * B_ + b) * K_ + j];
    for (int tb = 1; tb < T_; tb += 8) {
#pragma unroll
      for (int s = 0; s < 8; ++s) {
        const int t = tb + s;
        if (t < T_) {
          float e = er[s];
          if (t + 8 < T_) er[s] = emis[((t + 8) * B_ + b) * K_ + j];
          float sv[16];
          ALLGATHER16(sv, sc);
          float tv[16]; int ti[16];
#pragma unroll
          for (int i = 0; i < 16; ++i) { tv[i] = sv[i] + Tc[i]; ti[i] = i; }
#pragma unroll
          for (int st = 8; st >= 1; st >>= 1) {   // tournament, LOWER index wins ties (jnp.argmax)
#pragma unroll
            for (int i = 0; i < st; ++i) {
              bool cgt = tv[i + st] > tv[i];
              tv[i] = cgt ? tv[i + st] : tv[i];
              ti[i] = cgt ? ti[i + st] : ti[i];
            }
          }
          hist_lds[t * 64 + lane] = (unsigned char)ti[0];  // [t][b4][j], contiguous per wave
          float nxt = tv[0] + e;
          sc = (t < len) ? nxt : sc;
        }
      }
    }
    // argmax over final score + end (converges in all lanes of the 16-group)
    float v = sc + endv[j];
    int idx = j;
    { float ov = xshf16<1>(v); int oi = xshf16i<1>(idx); bool tk = (ov > v) || ((ov == v) && (oi < idx)); v = tk ? ov : v; idx = tk ? oi : idx; }
    { float ov = xshf16<2>(v); int oi = xshf16i<2>(idx); bool tk = (ov > v) || ((ov == v) && (oi < idx)); v = tk ? ov : v; idx = tk ? oi : idx; }
    { float ov = xshf16<4>(v); int oi = xshf16i<4>(idx); bool tk = (ov > v) || ((ov == v) && (oi < idx)); v = tk ? ov : v; idx = tk ? oi : idx; }
    { float ov = xshf16<8>(v); int oi = xshf16i<8>(idx); bool tk = (ov > v) || ((ov == v) && (oi < idx)); v = tk ? ov : v; idx = tk ? oi : idx; }
    int cur = idx;
    // ---- backtrack from LDS hist; 4-deep prefetch ring; same wave wrote it (lgkmcnt ordering) ----
    unsigned char hr[4];
#pragma unroll
    for (int s = 0; s < 4; ++s) hr[s] = hist_lds[(1023 - s) * 64 + lane];
    for (int tb = 1023; tb >= 1; tb -= 4) {
#pragma unroll
      for (int s = 0; s < 4; ++s) {
        const int t = tb - s;
        if (t >= 1) {
          int h = hr[s];
          if (t - 4 >= 1) hr[s] = hist_lds[(t - 4) * 64 + lane];
          bool m = (t < len);
          if (j == 0) out[b * T_ + t] = m ? (float)cur : 0.0f;  // tag BEFORE stepping
          int prev = __shfl(h, (lane & 48) | cur);
          cur = m ? prev : cur;
        }
      }
    }
    if (j == 0) out[b * T_] = (float)cur;

  } else {
    // ---- numerator: gather-sum, 16 lanes stride over t; unroll keeps gathers in flight ----
    const int* lab = labels + b * T_;
    float acc = 0.0f;
#pragma unroll 4
    for (int t = j; t < T_; t += 16) {
      int lt = lab[t];
      float e = emis[(t * B_ + b) * K_ + lt];
      if (t == 0) acc += start[lt] + e;                       // t=0 term is unmasked in reference
      else if (t < len) acc += trans[lab[t - 1] * K_ + lt] + e;
    }
    SUM16(acc);
    if (j == 0) num[b] = acc + endv[lab[len - 1]];
  }
}

// ---------- loss = -mean(num - logZ) ----------
__global__ void loss_kernel(const float* __restrict__ num, const float* __restrict__ logZ,
                            float* __restrict__ out) {
  int l = threadIdx.x;
  float s = (num[l] - logZ[l]) + (num[l + 64] - logZ[l + 64]);
#pragma unroll
  for (int m = 1; m < 64; m <<= 1) s += __shfl_xor(s, m);
  if (l == 0) out[B_ * T_] = -s / (float)B_;
}

extern "C" void kernel_launch(void* const* d_in, const int* in_sizes, int n_in,
                              void* d_out, int out_size, void* d_ws, size_t ws_size,
                              hipStream_t stream) {
  const float* H      = (const float*)d_in[0];
  const void*  maskp  = d_in[1];
  const int*   labels = (const int*)d_in[2];
  const float* W      = (const float*)d_in[3];
  const float* bias   = (const float*)d_in[4];
  const float* start  = (const float*)d_in[5];
  const float* trans  = (const float*)d_in[6];
  const float* endv   = (const float*)d_in[7];

  char* ws = (char*)d_ws;
  float* emis = (float*)ws;                       //  8 MB  emis[t][b][k]
  float* num  = (float*)(ws + 8388608);           //  512 B
  float* logZ = (float*)(ws + 8389120);           //  512 B
  int*   lens = (int*)(ws + 8389632);             //  512 B
  float* out  = (float*)d_out;                    //  pred (B*T floats) then loss

  len_kernel<<<dim3(B_), dim3(64), 0, stream>>>(maskp, lens);
  emis_kernel<<<dim3((B_ * T_) / 256), dim3(256), 0, stream>>>(H, W, bias, emis);
  crf_kernel<<<dim3(96), dim3(64), 0, stream>>>(emis, trans, start, endv, labels, lens,
                                                logZ, num, out);
  loss_kernel<<<dim3(1), dim3(64), 0, stream>>>(num, logZ, out);
}

// Round 3
// 2002.306 us; speedup vs baseline: 1.0444x; 1.0444x over previous
//
#include <hip/hip_runtime.h>

#define B_ 128
#define T_ 1024
#define D_ 512
#define K_ 16

// ---------- cross-lane helpers (16-lane groups inside wave64; ds_swizzle works per-32-lane half) ----------
template<int I>
__device__ __forceinline__ float bcast16(float v) {
  // lane' = (lane & 0x10) | I  -> broadcast lane I of each 16-group
  return __int_as_float(__builtin_amdgcn_ds_swizzle(__float_as_int(v), (I << 5) | 0x10));
}
template<int M>
__device__ __forceinline__ float xshf16(float v) {
  return __int_as_float(__builtin_amdgcn_ds_swizzle(__float_as_int(v), (M << 10) | 0x1F));
}
template<int M>
__device__ __forceinline__ int xshf16i(int v) {
  return __builtin_amdgcn_ds_swizzle(v, (M << 10) | 0x1F);
}

#define ALLGATHER16(sv, p) do { \
  sv[0]=bcast16<0>(p);  sv[1]=bcast16<1>(p);  sv[2]=bcast16<2>(p);  sv[3]=bcast16<3>(p);  \
  sv[4]=bcast16<4>(p);  sv[5]=bcast16<5>(p);  sv[6]=bcast16<6>(p);  sv[7]=bcast16<7>(p);  \
  sv[8]=bcast16<8>(p);  sv[9]=bcast16<9>(p);  sv[10]=bcast16<10>(p); sv[11]=bcast16<11>(p); \
  sv[12]=bcast16<12>(p); sv[13]=bcast16<13>(p); sv[14]=bcast16<14>(p); sv[15]=bcast16<15>(p); \
} while (0)

#define SUM16(s) do { s += xshf16<1>(s); s += xshf16<2>(s); s += xshf16<4>(s); s += xshf16<8>(s); } while (0)

// ---------- mask -> lengths (handles byte-bool OR int32 mask storage; mask[0][0] is always true) ----------
__global__ void len_kernel(const void* __restrict__ maskp, int* __restrict__ lens) {
  const int b = blockIdx.x;
  const int l = threadIdx.x;
  const int isInt = (((const int*)maskp)[0] == 1);  // byte storage would read 0x01010101 here
  int cnt = 0;
  if (isInt) {
    const int* m = (const int*)maskp + b * T_;
    for (int t = l; t < T_; t += 64) cnt += (m[t] != 0);
  } else {
    const unsigned char* m = (const unsigned char*)maskp + b * T_;
    for (int t = l; t < T_; t += 64) cnt += (m[t] != 0);
  }
#pragma unroll
  for (int s = 1; s < 64; s <<= 1) cnt += __shfl_xor(cnt, s);
  if (l == 0) lens[b] = cnt;
}

// ---------- emissions: logits[b][t][k] = dot(H[b][t][:], W[k][:]) + bias[k], stored as emis[t][b][k] ----------
__global__ __launch_bounds__(256) void emis_kernel(const float* __restrict__ H,
                                                   const float* __restrict__ W,
                                                   const float* __restrict__ bias,
                                                   float* __restrict__ emis) {
  __shared__ float Wt[D_ * K_];  // [d][k], 32 KB; reads are wave-uniform -> broadcast, conflict-free
  for (int idx = threadIdx.x; idx < D_ * K_; idx += 256) {
    int k = idx >> 9;        // W is (K, D) row-major
    int d = idx & (D_ - 1);
    Wt[d * K_ + k] = W[idx];
  }
  __syncthreads();
  const int r = blockIdx.x * 256 + threadIdx.x;  // row into (B*T)
  const float4* hrow = (const float4*)(H + (size_t)r * D_);
  float acc[16];
#pragma unroll
  for (int k = 0; k < 16; ++k) acc[k] = bias[k];
  float4 a[8], an[8];
#pragma unroll
  for (int u = 0; u < 8; ++u) a[u] = hrow[u];
  for (int c = 0; c < 16; ++c) {          // 16 chunks of 32 dims
    if (c < 15) {
#pragma unroll
      for (int u = 0; u < 8; ++u) an[u] = hrow[(c + 1) * 8 + u];  // prefetch next chunk under FMAs
    }
#pragma unroll
    for (int u = 0; u < 8; ++u) {
#pragma unroll
      for (int q = 0; q < 4; ++q) {
        const int d = c * 32 + u * 4 + q;
        const float4* wr = (const float4*)(Wt + d * K_);
        float x = (q == 0) ? a[u].x : (q == 1) ? a[u].y : (q == 2) ? a[u].z : a[u].w;
        float4 w0 = wr[0], w1 = wr[1], w2 = wr[2], w3 = wr[3];
        acc[0]  = fmaf(x, w0.x, acc[0]);  acc[1]  = fmaf(x, w0.y, acc[1]);
        acc[2]  = fmaf(x, w0.z, acc[2]);  acc[3]  = fmaf(x, w0.w, acc[3]);
        acc[4]  = fmaf(x, w1.x, acc[4]);  acc[5]  = fmaf(x, w1.y, acc[5]);
        acc[6]  = fmaf(x, w1.z, acc[6]);  acc[7]  = fmaf(x, w1.w, acc[7]);
        acc[8]  = fmaf(x, w2.x, acc[8]);  acc[9]  = fmaf(x, w2.y, acc[9]);
        acc[10] = fmaf(x, w2.z, acc[10]); acc[11] = fmaf(x, w2.w, acc[11]);
        acc[12] = fmaf(x, w3.x, acc[12]); acc[13] = fmaf(x, w3.y, acc[13]);
        acc[14] = fmaf(x, w3.z, acc[14]); acc[15] = fmaf(x, w3.w, acc[15]);
      }
    }
#pragma unroll
    for (int u = 0; u < 8; ++u) a[u] = an[u];
  }
  const int b = r >> 10;          // T_ = 1024
  const int t = r & (T_ - 1);
  float4* o = (float4*)(emis + ((size_t)t * B_ + b) * K_);
  o[0] = make_float4(acc[0], acc[1], acc[2], acc[3]);
  o[1] = make_float4(acc[4], acc[5], acc[6], acc[7]);
  o[2] = make_float4(acc[8], acc[9], acc[10], acc[11]);
  o[3] = make_float4(acc[12], acc[13], acc[14], acc[15]);
}

// ---------- CRF: blocks 0-31 logZ, 32-63 viterbi fwd+backtrack (hist in LDS), 64-95 numerator ----------
// 64 thr = 1 wave = 4 batches x 16 states. Single-wave block -> no __syncthreads needed for LDS reuse.
// NOTE (round-2 lesson): all prefetch is 2-deep via NAMED registers with CLAMPED indices — no
// conditional loads, no arrays. Conditional-load rings made the compiler drain vmcnt every step (5x).
__global__ __launch_bounds__(64) void crf_kernel(const float* __restrict__ emis,
                                                 const float* __restrict__ trans,
                                                 const float* __restrict__ start,
                                                 const float* __restrict__ endv,
                                                 const int* __restrict__ labels,
                                                 const int* __restrict__ lens,
                                                 float* __restrict__ logZ,
                                                 float* __restrict__ num,
                                                 float* __restrict__ out) {
  __shared__ unsigned char hist_lds[T_ * 64];  // [t][b4][j] = 64 KB (only role 1 touches it)
  const int role = blockIdx.x >> 5;
  const int blk  = blockIdx.x & 31;
  const int lane = threadIdx.x;
  const int j = lane & 15;
  const int b = blk * 4 + (lane >> 4);
  const int len = lens[b];

  if (role == 0) {
    // ---- logZ in probability domain; normalize every 8 steps; 2-deep clamped prefetch ----
    float Tc[16];
#pragma unroll
    for (int i = 0; i < 16; ++i) Tc[i] = __expf(trans[i * K_ + j]);  // column j of exp(trans)
    float p = __expf(start[j] + emis[b * K_ + j]);                   // t=0
    float c = 0.0f;
    float e1 = emis[(1 * B_ + b) * K_ + j];
    float e2 = emis[(2 * B_ + b) * K_ + j];
    for (int t = 1; t < T_; ++t) {
      float e = e1;
      e1 = e2;
      const int tn = (t + 2 < T_) ? (t + 2) : (T_ - 1);   // uniform scalar clamp, no branch
      e2 = emis[(tn * B_ + b) * K_ + j];
      float sv[16];
      ALLGATHER16(sv, p);
      float qa = fmaf(sv[0],  Tc[0],  fmaf(sv[1],  Tc[1],  fmaf(sv[2],  Tc[2],  sv[3]  * Tc[3])));
      float qb = fmaf(sv[4],  Tc[4],  fmaf(sv[5],  Tc[5],  fmaf(sv[6],  Tc[6],  sv[7]  * Tc[7])));
      float qc = fmaf(sv[8],  Tc[8],  fmaf(sv[9],  Tc[9],  fmaf(sv[10], Tc[10], sv[11] * Tc[11])));
      float qd = fmaf(sv[12], Tc[12], fmaf(sv[13], Tc[13], fmaf(sv[14], Tc[14], sv[15] * Tc[15])));
      float q = ((qa + qb) + (qc + qd)) * __expf(e);
      p = (t < len) ? q : p;          // masked step keeps old state
      if ((t & 7) == 0) {             // growth <= e^2.8/step; 8 steps safe in f32
        float S = p;
        SUM16(S);
        c += __logf(S);
        p *= __fdividef(1.0f, S);
      }
    }
    float u = p * __expf(endv[j]);
    SUM16(u);
    if (j == 0) logZ[b] = c + __logf(u);

  } else if (role == 1) {
    // ---- Viterbi forward (max-plus), hist in LDS, then in-kernel backtrack ----
    float Tc[16];
#pragma unroll
    for (int i = 0; i < 16; ++i) Tc[i] = trans[i * K_ + j];
    float sc = start[j] + emis[b * K_ + j];
    float e1 = emis[(1 * B_ + b) * K_ + j];
    float e2 = emis[(2 * B_ + b) * K_ + j];
    for (int t = 1; t < T_; ++t) {
      float e = e1;
      e1 = e2;
      const int tn = (t + 2 < T_) ? (t + 2) : (T_ - 1);
      e2 = emis[(tn * B_ + b) * K_ + j];
      float sv[16];
      ALLGATHER16(sv, sc);
      float tv[16]; int ti[16];
#pragma unroll
      for (int i = 0; i < 16; ++i) { tv[i] = sv[i] + Tc[i]; ti[i] = i; }
#pragma unroll
      for (int st = 8; st >= 1; st >>= 1) {   // tournament, LOWER index wins ties (jnp.argmax)
#pragma unroll
        for (int i = 0; i < st; ++i) {
          bool cgt = tv[i + st] > tv[i];
          tv[i] = cgt ? tv[i + st] : tv[i];
          ti[i] = cgt ? ti[i + st] : ti[i];
        }
      }
      hist_lds[t * 64 + lane] = (unsigned char)ti[0];  // [t][b4][j], contiguous per wave
      float nxt = tv[0] + e;
      sc = (t < len) ? nxt : sc;
    }
    // argmax over final score + end (converges in all lanes of the 16-group)
    float v = sc + endv[j];
    int idx = j;
    { float ov = xshf16<1>(v); int oi = xshf16i<1>(idx); bool tk = (ov > v) || ((ov == v) && (oi < idx)); v = tk ? ov : v; idx = tk ? oi : idx; }
    { float ov = xshf16<2>(v); int oi = xshf16i<2>(idx); bool tk = (ov > v) || ((ov == v) && (oi < idx)); v = tk ? ov : v; idx = tk ? oi : idx; }
    { float ov = xshf16<4>(v); int oi = xshf16i<4>(idx); bool tk = (ov > v) || ((ov == v) && (oi < idx)); v = tk ? ov : v; idx = tk ? oi : idx; }
    { float ov = xshf16<8>(v); int oi = xshf16i<8>(idx); bool tk = (ov > v) || ((ov == v) && (oi < idx)); v = tk ? ov : v; idx = tk ? oi : idx; }
    int cur = idx;
    // ---- backtrack from LDS hist; 1-deep clamped prefetch (off the shfl chain) ----
    int hb = hist_lds[1023 * 64 + lane];
    for (int t = 1023; t >= 1; --t) {
      int h = hb;
      const int tp = (t - 1 > 1) ? (t - 1) : 1;        // clamp; one redundant read at the tail
      hb = hist_lds[tp * 64 + lane];
      bool m = (t < len);
      if (j == 0) out[b * T_ + t] = m ? (float)cur : 0.0f;  // tag BEFORE stepping
      int prev = __shfl(h, (lane & 48) | cur);
      cur = m ? prev : cur;
    }
    if (j == 0) out[b * T_] = (float)cur;

  } else {
    // ---- numerator: gather-sum, 16 lanes stride over t (plain round-1 loop) ----
    const int* lab = labels + b * T_;
    float acc = 0.0f;
    for (int t = j; t < T_; t += 16) {
      int lt = lab[t];
      float e = emis[(t * B_ + b) * K_ + lt];
      if (t == 0) acc += start[lt] + e;                       // t=0 term is unmasked in reference
      else if (t < len) acc += trans[lab[t - 1] * K_ + lt] + e;
    }
    SUM16(acc);
    if (j == 0) num[b] = acc + endv[lab[len - 1]];
  }
}

// ---------- loss = -mean(num - logZ) ----------
__global__ void loss_kernel(const float* __restrict__ num, const float* __restrict__ logZ,
                            float* __restrict__ out) {
  int l = threadIdx.x;
  float s = (num[l] - logZ[l]) + (num[l + 64] - logZ[l + 64]);
#pragma unroll
  for (int m = 1; m < 64; m <<= 1) s += __shfl_xor(s, m);
  if (l == 0) out[B_ * T_] = -s / (float)B_;
}

extern "C" void kernel_launch(void* const* d_in, const int* in_sizes, int n_in,
                              void* d_out, int out_size, void* d_ws, size_t ws_size,
                              hipStream_t stream) {
  const float* H      = (const float*)d_in[0];
  const void*  maskp  = d_in[1];
  const int*   labels = (const int*)d_in[2];
  const float* W      = (const float*)d_in[3];
  const float* bias   = (const float*)d_in[4];
  const float* start  = (const float*)d_in[5];
  const float* trans  = (const float*)d_in[6];
  const float* endv   = (const float*)d_in[7];

  char* ws = (char*)d_ws;
  float* emis = (float*)ws;                       //  8 MB  emis[t][b][k]
  float* num  = (float*)(ws + 8388608);           //  512 B
  float* logZ = (float*)(ws + 8389120);           //  512 B
  int*   lens = (int*)(ws + 8389632);             //  512 B
  float* out  = (float*)d_out;                    //  pred (B*T floats) then loss

  len_kernel<<<dim3(B_), dim3(64), 0, stream>>>(maskp, lens);
  emis_kernel<<<dim3((B_ * T_) / 256), dim3(256), 0, stream>>>(H, W, bias, emis);
  crf_kernel<<<dim3(96), dim3(64), 0, stream>>>(emis, trans, start, endv, labels, lens,
                                                logZ, num, out);
  loss_kernel<<<dim3(1), dim3(64), 0, stream>>>(num, logZ, out);
}

// Round 4
// 684.756 us; speedup vs baseline: 3.0539x; 2.9241x over previous
//
#include <hip/hip_runtime.h>

#define B_ 128
#define T_ 1024
#define D_ 512
#define K_ 16
#define NCH 32   // chunks
#define CSZ 32   // steps per chunk

// ---------- cross-lane helpers (16-lane groups; ds_swizzle acts within 32-lane halves) ----------
template<int I>
__device__ __forceinline__ float bcast16(float v) {
  return __int_as_float(__builtin_amdgcn_ds_swizzle(__float_as_int(v), (I << 5) | 0x10));
}
template<int M>
__device__ __forceinline__ float xshf16(float v) {
  return __int_as_float(__builtin_amdgcn_ds_swizzle(__float_as_int(v), (M << 10) | 0x1F));
}
template<int M>
__device__ __forceinline__ int xshf16i(int v) {
  return __builtin_amdgcn_ds_swizzle(v, (M << 10) | 0x1F);
}

#define ALLGATHER16(sv, p) do { \
  sv[0]=bcast16<0>(p);  sv[1]=bcast16<1>(p);  sv[2]=bcast16<2>(p);  sv[3]=bcast16<3>(p);  \
  sv[4]=bcast16<4>(p);  sv[5]=bcast16<5>(p);  sv[6]=bcast16<6>(p);  sv[7]=bcast16<7>(p);  \
  sv[8]=bcast16<8>(p);  sv[9]=bcast16<9>(p);  sv[10]=bcast16<10>(p); sv[11]=bcast16<11>(p); \
  sv[12]=bcast16<12>(p); sv[13]=bcast16<13>(p); sv[14]=bcast16<14>(p); sv[15]=bcast16<15>(p); \
} while (0)

#define SUM16(s) do { s += xshf16<1>(s); s += xshf16<2>(s); s += xshf16<4>(s); s += xshf16<8>(s); } while (0)

template<int M> __device__ __forceinline__ void bsum_round(float* pn) {
#pragma unroll
  for (int j = 0; j < 16; ++j) pn[j] += xshf16<M>(pn[j]);
}
template<int M> __device__ __forceinline__ void bmax_round(float* val, int* idx) {
#pragma unroll
  for (int j = 0; j < 16; ++j) {
    float ov = xshf16<M>(val[j]); int oi = xshf16i<M>(idx[j]);
    bool tk = (ov > val[j]) || ((ov == val[j]) && (oi < idx[j]));
    val[j] = tk ? ov : val[j]; idx[j] = tk ? oi : idx[j];
  }
}

// ---------- mask -> lengths (byte-bool OR int32 storage; mask[0][0] always true) ----------
__global__ void len_kernel(const void* __restrict__ maskp, int* __restrict__ lens) {
  const int b = blockIdx.x;
  const int l = threadIdx.x;
  const int isInt = (((const int*)maskp)[0] == 1);
  int cnt = 0;
  if (isInt) {
    const int* m = (const int*)maskp + b * T_;
    for (int t = l; t < T_; t += 64) cnt += (m[t] != 0);
  } else {
    const unsigned char* m = (const unsigned char*)maskp + b * T_;
    for (int t = l; t < T_; t += 64) cnt += (m[t] != 0);
  }
#pragma unroll
  for (int s = 1; s < 64; s <<= 1) cnt += __shfl_xor(cnt, s);
  if (l == 0) lens[b] = cnt;
}

// ---------- emissions: emis[t][b][k] = dot(H[b][t][:], W[k][:]) + b[k] ----------
__global__ __launch_bounds__(256) void emis_kernel(const float* __restrict__ H,
                                                   const float* __restrict__ W,
                                                   const float* __restrict__ bias,
                                                   float* __restrict__ emis) {
  __shared__ float Wt[D_ * K_];  // [d][k]; wave-uniform reads -> broadcast
  for (int idx = threadIdx.x; idx < D_ * K_; idx += 256) {
    int k = idx >> 9;
    int d = idx & (D_ - 1);
    Wt[d * K_ + k] = W[idx];
  }
  __syncthreads();
  const int r = blockIdx.x * 256 + threadIdx.x;
  const float4* hrow = (const float4*)(H + (size_t)r * D_);
  float acc[16];
#pragma unroll
  for (int k = 0; k < 16; ++k) acc[k] = bias[k];
  float4 a[8], an[8];
#pragma unroll
  for (int u = 0; u < 8; ++u) a[u] = hrow[u];
  for (int c = 0; c < 16; ++c) {
    if (c < 15) {
#pragma unroll
      for (int u = 0; u < 8; ++u) an[u] = hrow[(c + 1) * 8 + u];
    }
#pragma unroll
    for (int u = 0; u < 8; ++u) {
#pragma unroll
      for (int q = 0; q < 4; ++q) {
        const int d = c * 32 + u * 4 + q;
        const float4* wr = (const float4*)(Wt + d * K_);
        float x = (q == 0) ? a[u].x : (q == 1) ? a[u].y : (q == 2) ? a[u].z : a[u].w;
        float4 w0 = wr[0], w1 = wr[1], w2 = wr[2], w3 = wr[3];
        acc[0]  = fmaf(x, w0.x, acc[0]);  acc[1]  = fmaf(x, w0.y, acc[1]);
        acc[2]  = fmaf(x, w0.z, acc[2]);  acc[3]  = fmaf(x, w0.w, acc[3]);
        acc[4]  = fmaf(x, w1.x, acc[4]);  acc[5]  = fmaf(x, w1.y, acc[5]);
        acc[6]  = fmaf(x, w1.z, acc[6]);  acc[7]  = fmaf(x, w1.w, acc[7]);
        acc[8]  = fmaf(x, w2.x, acc[8]);  acc[9]  = fmaf(x, w2.y, acc[9]);
        acc[10] = fmaf(x, w2.z, acc[10]); acc[11] = fmaf(x, w2.w, acc[11]);
        acc[12] = fmaf(x, w3.x, acc[12]); acc[13] = fmaf(x, w3.y, acc[13]);
        acc[14] = fmaf(x, w3.z, acc[14]); acc[15] = fmaf(x, w3.w, acc[15]);
      }
    }
#pragma unroll
    for (int u = 0; u < 8; ++u) a[u] = an[u];
  }
  const int b = r >> 10;
  const int t = r & (T_ - 1);
  float4* o = (float4*)(emis + ((size_t)t * B_ + b) * K_);
  o[0] = make_float4(acc[0], acc[1], acc[2], acc[3]);
  o[1] = make_float4(acc[4], acc[5], acc[6], acc[7]);
  o[2] = make_float4(acc[8], acc[9], acc[10], acc[11]);
  o[3] = make_float4(acc[12], acc[13], acc[14], acc[15]);
}

// ---------- phase 1: per-(batch,chunk) 16x16 semiring matrices; lane = matrix COLUMN ----------
// blocks 0..1023: logZ ((+,*) with per-column log-scale); 1024..2047: Viterbi ((max,+)).
// job = blk*4 + g; b = blk>>3 (uniform per wave); ch = (blk&7)*4 + g. Lane-local recursion!
__global__ __launch_bounds__(64) void phase1_kernel(const float* __restrict__ emis,
                                                    const float* __restrict__ trans,
                                                    const int* __restrict__ lens,
                                                    float* __restrict__ Mz,
                                                    float* __restrict__ Lz,
                                                    float* __restrict__ Mv) {
  __shared__ float Wl[256];           // [j][i] = (exp)trans[i][j]
  __shared__ float tile[128 * 16];    // 128 t-rows of (exp)emis for this wave's 4 chunks, 8 KB
  const int lane = threadIdx.x;
  const int g = lane >> 4, c = lane & 15;
  const bool isZ = (blockIdx.x < 1024);
  const int blk = isZ ? blockIdx.x : (blockIdx.x - 1024);
  const int b = blk >> 3;
  const int ch = (blk & 7) * 4 + g;
  const int len = lens[b];
  // stage transposed transition matrix
#pragma unroll
  for (int pp = 0; pp < 4; ++pp) {
    int flat = pp * 64 + lane; int j = flat >> 4, i = flat & 15;
    float tv = trans[i * 16 + j];
    Wl[flat] = isZ ? __expf(tv) : tv;
  }
  // stage emission rows t0..t0+127 (clamped); exp() for logZ role
  const int t0 = 128 * (blk & 7) + 1;
#pragma unroll
  for (int pp = 0; pp < 8; ++pp) {
    int flat = pp * 64 + lane;              // float4 units
    int row = flat >> 2, q = flat & 3;
    int t = t0 + row; t = (t < 1023) ? t : 1023;
    float4 v4 = *(const float4*)(emis + ((size_t)t * B_ + b) * K_ + q * 4);
    if (isZ) { v4.x = __expf(v4.x); v4.y = __expf(v4.y); v4.z = __expf(v4.z); v4.w = __expf(v4.w); }
    *(float4*)&tile[row * 16 + q * 4] = v4;
  }
  __syncthreads();

  if (isZ) {
    float v[16];
#pragma unroll
    for (int i = 0; i < 16; ++i) v[i] = (i == c) ? 1.0f : 0.0f;
    float ell = 0.0f;
    for (int s = 0; s < CSZ; ++s) {
      const int t = ch * CSZ + 1 + s;
      const float* xr = &tile[(g * 32 + s) * 16];
      float4 x0 = *(const float4*)(xr), x1 = *(const float4*)(xr + 4),
             x2 = *(const float4*)(xr + 8), x3 = *(const float4*)(xr + 12);
      float xs[16] = {x0.x, x0.y, x0.z, x0.w, x1.x, x1.y, x1.z, x1.w,
                      x2.x, x2.y, x2.z, x2.w, x3.x, x3.y, x3.z, x3.w};
      float nv[16];
#pragma unroll
      for (int j = 0; j < 16; ++j) {
        const float* wr = &Wl[j * 16];
        float4 w0 = *(const float4*)(wr), w1 = *(const float4*)(wr + 4),
               w2 = *(const float4*)(wr + 8), w3 = *(const float4*)(wr + 12);
        float a;
        a = v[0] * w0.x;        a = fmaf(v[1], w0.y, a); a = fmaf(v[2], w0.z, a); a = fmaf(v[3], w0.w, a);
        a = fmaf(v[4], w1.x, a); a = fmaf(v[5], w1.y, a); a = fmaf(v[6], w1.z, a); a = fmaf(v[7], w1.w, a);
        a = fmaf(v[8], w2.x, a); a = fmaf(v[9], w2.y, a); a = fmaf(v[10], w2.z, a); a = fmaf(v[11], w2.w, a);
        a = fmaf(v[12], w3.x, a); a = fmaf(v[13], w3.y, a); a = fmaf(v[14], w3.z, a); a = fmaf(v[15], w3.w, a);
        nv[j] = a * xs[j];
      }
      const bool keep = (t < len);
#pragma unroll
      for (int j = 0; j < 16; ++j) v[j] = keep ? nv[j] : v[j];
      float S = (((v[0] + v[1]) + (v[2] + v[3])) + ((v[4] + v[5]) + (v[6] + v[7]))) +
                (((v[8] + v[9]) + (v[10] + v[11])) + ((v[12] + v[13]) + (v[14] + v[15])));
      float inv = __fdividef(1.0f, S);
      ell += __logf(S);
#pragma unroll
      for (int j = 0; j < 16; ++j) v[j] *= inv;
    }
    float* dst = Mz + (((size_t)(b * NCH + ch) * 16) + c) * 16;
    *(float4*)(dst + 0)  = make_float4(v[0], v[1], v[2], v[3]);
    *(float4*)(dst + 4)  = make_float4(v[4], v[5], v[6], v[7]);
    *(float4*)(dst + 8)  = make_float4(v[8], v[9], v[10], v[11]);
    *(float4*)(dst + 12) = make_float4(v[12], v[13], v[14], v[15]);
    Lz[(b * NCH + ch) * 16 + c] = ell;
  } else {
    float v[16];
#pragma unroll
    for (int i = 0; i < 16; ++i) v[i] = (i == c) ? 0.0f : -1e30f;
    for (int s = 0; s < CSZ; ++s) {
      const int t = ch * CSZ + 1 + s;
      const float* xr = &tile[(g * 32 + s) * 16];
      float4 x0 = *(const float4*)(xr), x1 = *(const float4*)(xr + 4),
             x2 = *(const float4*)(xr + 8), x3 = *(const float4*)(xr + 12);
      float es[16] = {x0.x, x0.y, x0.z, x0.w, x1.x, x1.y, x1.z, x1.w,
                      x2.x, x2.y, x2.z, x2.w, x3.x, x3.y, x3.z, x3.w};
      float nv[16];
#pragma unroll
      for (int j = 0; j < 16; ++j) {
        const float* wr = &Wl[j * 16];
        float4 w0 = *(const float4*)(wr), w1 = *(const float4*)(wr + 4),
               w2 = *(const float4*)(wr + 8), w3 = *(const float4*)(wr + 12);
        float a0 = v[0] + w0.x,  a1 = v[1] + w0.y,  a2 = v[2] + w0.z,  a3 = v[3] + w0.w;
        float a4 = v[4] + w1.x,  a5 = v[5] + w1.y,  a6 = v[6] + w1.z,  a7 = v[7] + w1.w;
        float a8 = v[8] + w2.x,  a9 = v[9] + w2.y,  a10 = v[10] + w2.z, a11 = v[11] + w2.w;
        float a12 = v[12] + w3.x, a13 = v[13] + w3.y, a14 = v[14] + w3.z, a15 = v[15] + w3.w;
        float m = fmaxf(fmaxf(fmaxf(fmaxf(a0, a1), fmaxf(a2, a3)), fmaxf(fmaxf(a4, a5), fmaxf(a6, a7))),
                        fmaxf(fmaxf(fmaxf(a8, a9), fmaxf(a10, a11)), fmaxf(fmaxf(a12, a13), fmaxf(a14, a15))));
        nv[j] = m + es[j];
      }
      const bool keep = (t < len);
#pragma unroll
      for (int j = 0; j < 16; ++j) v[j] = keep ? nv[j] : v[j];
    }
    float* dst = Mv + (((size_t)(b * NCH + ch) * 16) + c) * 16;
    *(float4*)(dst + 0)  = make_float4(v[0], v[1], v[2], v[3]);
    *(float4*)(dst + 4)  = make_float4(v[4], v[5], v[6], v[7]);
    *(float4*)(dst + 8)  = make_float4(v[8], v[9], v[10], v[11]);
    *(float4*)(dst + 12) = make_float4(v[12], v[13], v[14], v[15]);
  }
}

// ---------- phase 2: blocks 0-31 logZ combine; 32-63 viterbi combine+boundary bt; 64-95 numerator ----------
__global__ __launch_bounds__(64) void phase2_kernel(const float* __restrict__ emis,
                                                    const float* __restrict__ trans,
                                                    const float* __restrict__ start,
                                                    const float* __restrict__ endv,
                                                    const int* __restrict__ labels,
                                                    const int* __restrict__ lens,
                                                    const float* __restrict__ Mz,
                                                    const float* __restrict__ Lz,
                                                    const float* __restrict__ Mv,
                                                    float* __restrict__ logZ,
                                                    int* __restrict__ states,
                                                    float* __restrict__ num) {
  __shared__ unsigned char Bh[4][NCH][16];
  const int role = blockIdx.x >> 5;
  const int blk  = blockIdx.x & 31;
  const int lane = threadIdx.x;
  const int g = lane >> 4, c = lane & 15;
  const int b = blk * 4 + g;

  if (role == 0) {
    // lane c carries p[c]; chunk combine: p_next[j] = sum_c p[c]*e^{ell_c}*Mz[c][j]
    float pc = __expf(start[c] + emis[b * K_ + c]);    // f(0), t=0 unmasked
    float S0 = pc; SUM16(S0);
    float L = __logf(S0);
    pc = __fdividef(pc, S0);
    for (int ch = 0; ch < NCH; ++ch) {
      const float* src = Mz + (((size_t)(b * NCH + ch) * 16) + c) * 16;
      float4 m0 = *(const float4*)(src), m1 = *(const float4*)(src + 4),
             m2 = *(const float4*)(src + 8), m3 = *(const float4*)(src + 12);
      float ellc = Lz[(b * NCH + ch) * 16 + c];
      float me = ellc;
      me = fmaxf(me, xshf16<1>(me)); me = fmaxf(me, xshf16<2>(me));
      me = fmaxf(me, xshf16<4>(me)); me = fmaxf(me, xshf16<8>(me));
      float w = pc * __expf(ellc - me);
      float pn[16] = {w * m0.x, w * m0.y, w * m0.z, w * m0.w, w * m1.x, w * m1.y, w * m1.z, w * m1.w,
                      w * m2.x, w * m2.y, w * m2.z, w * m2.w, w * m3.x, w * m3.y, w * m3.z, w * m3.w};
      bsum_round<1>(pn); bsum_round<2>(pn); bsum_round<4>(pn); bsum_round<8>(pn);
      float S = (((pn[0] + pn[1]) + (pn[2] + pn[3])) + ((pn[4] + pn[5]) + (pn[6] + pn[7]))) +
                (((pn[8] + pn[9]) + (pn[10] + pn[11])) + ((pn[12] + pn[13]) + (pn[14] + pn[15])));
      L += me + __logf(S);
      float pcs = pn[0];
#pragma unroll
      for (int k = 1; k < 16; ++k) pcs = (c == k) ? pn[k] : pcs;
      pc = __fdividef(pcs, S);
    }
    float u = pc * __expf(endv[c]);
    SUM16(u);
    if (c == 0) logZ[b] = L + __logf(u);

  } else if (role == 1) {
    float gc = start[c] + emis[b * K_ + c];
    float gv[16];
    for (int ch = 0; ch < NCH; ++ch) {
      const float* src = Mv + (((size_t)(b * NCH + ch) * 16) + c) * 16;
      float4 m0 = *(const float4*)(src), m1 = *(const float4*)(src + 4),
             m2 = *(const float4*)(src + 8), m3 = *(const float4*)(src + 12);
      float val[16] = {gc + m0.x, gc + m0.y, gc + m0.z, gc + m0.w, gc + m1.x, gc + m1.y, gc + m1.z, gc + m1.w,
                       gc + m2.x, gc + m2.y, gc + m2.z, gc + m2.w, gc + m3.x, gc + m3.y, gc + m3.z, gc + m3.w};
      int idx[16];
#pragma unroll
      for (int j = 0; j < 16; ++j) idx[j] = c;
      bmax_round<1>(val, idx); bmax_round<2>(val, idx); bmax_round<4>(val, idx); bmax_round<8>(val, idx);
      if (c == 0) {
#pragma unroll
        for (int j = 0; j < 16; ++j) Bh[g][ch][j] = (unsigned char)idx[j];
      }
#pragma unroll
      for (int j = 0; j < 16; ++j) gv[j] = val[j];
      float gn = gv[0];
#pragma unroll
      for (int k = 1; k < 16; ++k) gn = (c == k) ? gv[k] : gn;
      gc = gn;
    }
    // final argmax over j (first-index wins); all lanes identical
    float tv[16]; int ti[16];
#pragma unroll
    for (int j = 0; j < 16; ++j) { tv[j] = gv[j] + endv[j]; ti[j] = j; }
#pragma unroll
    for (int st = 8; st >= 1; st >>= 1) {
#pragma unroll
      for (int i = 0; i < st; ++i) {
        bool cgt = tv[i + st] > tv[i];
        tv[i] = cgt ? tv[i + st] : tv[i];
        ti[i] = cgt ? ti[i + st] : ti[i];
      }
    }
    __syncthreads();
    int sc = ti[0];
    if (c == 0) states[b * (NCH + 1) + NCH] = sc;
    for (int ch = NCH - 1; ch >= 0; --ch) {
      sc = Bh[g][ch][sc];
      if (c == 0) states[b * (NCH + 1) + ch] = sc;
    }

  } else {
    const int len = lens[b];
    const int* lab = labels + b * T_;
    float acc = 0.0f;
    for (int t = c; t < T_; t += 16) {
      int lt = lab[t];
      float e = emis[(t * B_ + b) * K_ + lt];
      if (t == 0) acc += start[lt] + e;
      else if (t < len) acc += trans[lab[t - 1] * K_ + lt] + e;
    }
    SUM16(acc);
    if (c == 0) num[b] = acc + endv[lab[len - 1]];
  }
}

// ---------- phase 3: re-run each viterbi chunk from known entry state; backtrack in-chunk ----------
__global__ __launch_bounds__(64) void phase3_kernel(const float* __restrict__ emis,
                                                    const float* __restrict__ trans,
                                                    const int* __restrict__ lens,
                                                    const int* __restrict__ states,
                                                    float* __restrict__ out) {
  __shared__ float tile[128 * 16];               // raw e rows, 8 KB
  __shared__ unsigned char hist_lds[CSZ * 64];   // [s][lane], 2 KB
  const int lane = threadIdx.x;
  const int g = lane >> 4, j = lane & 15;
  const int blk = blockIdx.x;
  const int b = blk >> 3;
  const int ch = (blk & 7) * 4 + g;
  const int len = lens[b];
  const int t0 = 128 * (blk & 7) + 1;
#pragma unroll
  for (int pp = 0; pp < 8; ++pp) {
    int flat = pp * 64 + lane;
    int row = flat >> 2, q = flat & 3;
    int t = t0 + row; t = (t < 1023) ? t : 1023;
    *(float4*)&tile[row * 16 + q * 4] = *(const float4*)(emis + ((size_t)t * B_ + b) * K_ + q * 4);
  }
  __syncthreads();
  const int s_in  = states[b * (NCH + 1) + ch];
  const int s_out = states[b * (NCH + 1) + ch + 1];
  float Tc[16];
#pragma unroll
  for (int i = 0; i < 16; ++i) Tc[i] = trans[i * K_ + j];   // column j
  float sc = (j == s_in) ? 0.0f : -1e30f;
  for (int s = 0; s < CSZ; ++s) {
    const int t = ch * CSZ + 1 + s;
    float e = tile[(g * 32 + s) * 16 + j];
    float sv[16];
    ALLGATHER16(sv, sc);
    float tv[16]; int ti[16];
#pragma unroll
    for (int i = 0; i < 16; ++i) { tv[i] = sv[i] + Tc[i]; ti[i] = i; }
#pragma unroll
    for (int st = 8; st >= 1; st >>= 1) {
#pragma unroll
      for (int i = 0; i < st; ++i) {
        bool cgt = tv[i + st] > tv[i];
        tv[i] = cgt ? tv[i + st] : tv[i];
        ti[i] = cgt ? ti[i + st] : ti[i];
      }
    }
    hist_lds[s * 64 + lane] = (unsigned char)ti[0];
    float nxt = tv[0] + e;
    sc = (t < len) ? nxt : sc;    // t>=1024 (ch=31,s=31) is masked since len<=1024
  }
  // backtrack within chunk from exit state
  int cur = s_out;
  for (int s = CSZ - 1; s >= 0; --s) {
    const int t = ch * CSZ + 1 + s;
    if (t < T_) {
      bool m = (t < len);
      if (j == 0) out[b * T_ + t] = m ? (float)cur : 0.0f;   // tag BEFORE stepping
      int h = hist_lds[s * 64 + lane];
      int prev = __shfl(h, (lane & 48) | cur);
      cur = m ? prev : cur;
    }
  }
  if (ch == 0 && j == 0) out[b * T_] = (float)cur;
}

// ---------- loss = -mean(num - logZ) ----------
__global__ void loss_kernel(const float* __restrict__ num, const float* __restrict__ logZ,
                            float* __restrict__ out) {
  int l = threadIdx.x;
  float s = (num[l] - logZ[l]) + (num[l + 64] - logZ[l + 64]);
#pragma unroll
  for (int m = 1; m < 64; m <<= 1) s += __shfl_xor(s, m);
  if (l == 0) out[B_ * T_] = -s / (float)B_;
}

extern "C" void kernel_launch(void* const* d_in, const int* in_sizes, int n_in,
                              void* d_out, int out_size, void* d_ws, size_t ws_size,
                              hipStream_t stream) {
  const float* H      = (const float*)d_in[0];
  const void*  maskp  = d_in[1];
  const int*   labels = (const int*)d_in[2];
  const float* W      = (const float*)d_in[3];
  const float* bias   = (const float*)d_in[4];
  const float* start  = (const float*)d_in[5];
  const float* trans  = (const float*)d_in[6];
  const float* endv   = (const float*)d_in[7];

  char* ws = (char*)d_ws;
  float* emis  = (float*)ws;                         //  8 MB   emis[t][b][k]
  float* Mz    = (float*)(ws + 8388608);             //  4 MB   [b][ch][c][j]
  float* Lz    = (float*)(ws + 12582912);            //  256 KB [b][ch][c]
  float* Mv    = (float*)(ws + 12845056);            //  4 MB   [b][ch][c][j]
  int*   states= (int*)  (ws + 17039360);            //  17 KB  [b][33]
  float* num   = (float*)(ws + 17056256);            //  512 B
  float* logZ  = (float*)(ws + 17056768);            //  512 B
  int*   lens  = (int*)  (ws + 17057280);            //  512 B
  float* out   = (float*)d_out;

  len_kernel<<<dim3(B_), dim3(64), 0, stream>>>(maskp, lens);
  emis_kernel<<<dim3((B_ * T_) / 256), dim3(256), 0, stream>>>(H, W, bias, emis);
  phase1_kernel<<<dim3(2048), dim3(64), 0, stream>>>(emis, trans, lens, Mz, Lz, Mv);
  phase2_kernel<<<dim3(96), dim3(64), 0, stream>>>(emis, trans, start, endv, labels, lens,
                                                   Mz, Lz, Mv, logZ, states, num);
  phase3_kernel<<<dim3(1024), dim3(64), 0, stream>>>(emis, trans, lens, states, out);
  loss_kernel<<<dim3(1), dim3(64), 0, stream>>>(num, logZ, out);
}

// Round 6
// 540.011 us; speedup vs baseline: 3.8724x; 1.2680x over previous
//
#include <hip/hip_runtime.h>

#define B_ 128
#define T_ 1024
#define D_ 512
#define K_ 16
#define NCH 32   // chunks
#define CSZ 32   // steps per chunk

// ---------- cross-lane helpers (16-lane groups; ds_swizzle acts within 32-lane halves) ----------
template<int I>
__device__ __forceinline__ float bcast16(float v) {
  return __int_as_float(__builtin_amdgcn_ds_swizzle(__float_as_int(v), (I << 5) | 0x10));
}
template<int M>
__device__ __forceinline__ float xshf16(float v) {
  return __int_as_float(__builtin_amdgcn_ds_swizzle(__float_as_int(v), (M << 10) | 0x1F));
}
template<int M>
__device__ __forceinline__ int xshf16i(int v) {
  return __builtin_amdgcn_ds_swizzle(v, (M << 10) | 0x1F);
}

#define ALLGATHER16(sv, p) do { \
  sv[0]=bcast16<0>(p);  sv[1]=bcast16<1>(p);  sv[2]=bcast16<2>(p);  sv[3]=bcast16<3>(p);  \
  sv[4]=bcast16<4>(p);  sv[5]=bcast16<5>(p);  sv[6]=bcast16<6>(p);  sv[7]=bcast16<7>(p);  \
  sv[8]=bcast16<8>(p);  sv[9]=bcast16<9>(p);  sv[10]=bcast16<10>(p); sv[11]=bcast16<11>(p); \
  sv[12]=bcast16<12>(p); sv[13]=bcast16<13>(p); sv[14]=bcast16<14>(p); sv[15]=bcast16<15>(p); \
} while (0)

#define SUM16(s) do { s += xshf16<1>(s); s += xshf16<2>(s); s += xshf16<4>(s); s += xshf16<8>(s); } while (0)
#define SUM32(s) do { s += xshf16<1>(s); s += xshf16<2>(s); s += xshf16<4>(s); s += xshf16<8>(s); s += xshf16<16>(s); } while (0)

// ---------- emissions + fused len: emis[t][b][k] = dot(H[b][t][:], W[k][:]) + b[k] ----------
__global__ __launch_bounds__(256) void emis_kernel(const float* __restrict__ H,
                                                   const float* __restrict__ W,
                                                   const float* __restrict__ bias,
                                                   const void* __restrict__ maskp,
                                                   float* __restrict__ emis,
                                                   int* __restrict__ lens) {
  __shared__ float Wt[D_ * K_];  // [d][k]; wave-uniform reads -> broadcast
  for (int idx = threadIdx.x; idx < D_ * K_; idx += 256) {
    int k = idx >> 9;
    int d = idx & (D_ - 1);
    Wt[d * K_ + k] = W[idx];
  }
  __syncthreads();
  const int r = blockIdx.x * 256 + threadIdx.x;
  const float4* hrow = (const float4*)(H + (size_t)r * D_);
  float acc[16];
#pragma unroll
  for (int k = 0; k < 16; ++k) acc[k] = bias[k];
  float4 a[8], an[8];
#pragma unroll
  for (int u = 0; u < 8; ++u) a[u] = hrow[u];
  for (int c = 0; c < 16; ++c) {
    if (c < 15) {
#pragma unroll
      for (int u = 0; u < 8; ++u) an[u] = hrow[(c + 1) * 8 + u];
    }
#pragma unroll
    for (int u = 0; u < 8; ++u) {
#pragma unroll
      for (int q = 0; q < 4; ++q) {
        const int d = c * 32 + u * 4 + q;
        const float4* wr = (const float4*)(Wt + d * K_);
        float x = (q == 0) ? a[u].x : (q == 1) ? a[u].y : (q == 2) ? a[u].z : a[u].w;
        float4 w0 = wr[0], w1 = wr[1], w2 = wr[2], w3 = wr[3];
        acc[0]  = fmaf(x, w0.x, acc[0]);  acc[1]  = fmaf(x, w0.y, acc[1]);
        acc[2]  = fmaf(x, w0.z, acc[2]);  acc[3]  = fmaf(x, w0.w, acc[3]);
        acc[4]  = fmaf(x, w1.x, acc[4]);  acc[5]  = fmaf(x, w1.y, acc[5]);
        acc[6]  = fmaf(x, w1.z, acc[6]);  acc[7]  = fmaf(x, w1.w, acc[7]);
        acc[8]  = fmaf(x, w2.x, acc[8]);  acc[9]  = fmaf(x, w2.y, acc[9]);
        acc[10] = fmaf(x, w2.z, acc[10]); acc[11] = fmaf(x, w2.w, acc[11]);
        acc[12] = fmaf(x, w3.x, acc[12]); acc[13] = fmaf(x, w3.y, acc[13]);
        acc[14] = fmaf(x, w3.z, acc[14]); acc[15] = fmaf(x, w3.w, acc[15]);
      }
    }
#pragma unroll
    for (int u = 0; u < 8; ++u) a[u] = an[u];
  }
  const int b = r >> 10;
  const int t = r & (T_ - 1);
  float4* o = (float4*)(emis + ((size_t)t * B_ + b) * K_);
  o[0] = make_float4(acc[0], acc[1], acc[2], acc[3]);
  o[1] = make_float4(acc[4], acc[5], acc[6], acc[7]);
  o[2] = make_float4(acc[8], acc[9], acc[10], acc[11]);
  o[3] = make_float4(acc[12], acc[13], acc[14], acc[15]);
  // ---- fused len: blocks 0..127, lanes 0..63 compute lens[blockIdx.x] ----
  if (blockIdx.x < B_ && threadIdx.x < 64) {
    const int bb = blockIdx.x;
    const int l = threadIdx.x;
    const int isInt = (((const int*)maskp)[0] == 1);  // byte storage reads 0x01010101 here
    int cnt = 0;
    if (isInt) {
      const int* m = (const int*)maskp + bb * T_;
      for (int tt = l; tt < T_; tt += 64) cnt += (m[tt] != 0);
    } else {
      const unsigned char* m = (const unsigned char*)maskp + bb * T_;
      for (int tt = l; tt < T_; tt += 64) cnt += (m[tt] != 0);
    }
#pragma unroll
    for (int s = 1; s < 64; s <<= 1) cnt += __shfl_xor(cnt, s);
    if (l == 0) lens[bb] = cnt;
  }
}

// ---------- phase 1: per-(batch,chunk) 16x16 semiring matrices; lane = matrix ROW c ----------
// blocks 0..1023: logZ ((+,*), per-row log-scale, normalize every 4 steps); 1024..2047: Viterbi ((max,+)).
// Output stored TRANSPOSED: M*[ (b*NCH+ch)*256 + j*16 + c ] = M[c][j]  (so phase2 lane l reads column l contiguously)
__global__ __launch_bounds__(64) void phase1_kernel(const float* __restrict__ emis,
                                                    const float* __restrict__ trans,
                                                    const int* __restrict__ lens,
                                                    float* __restrict__ Mz,
                                                    float* __restrict__ Lz,
                                                    float* __restrict__ Mv) {
  __shared__ float Wl[256];           // [j][i] = (exp)trans[i][j]
  __shared__ float tile[128 * 16];    // 128 t-rows of (exp)emis for this wave's 4 chunks, 8 KB
  const int lane = threadIdx.x;
  const int g = lane >> 4, c = lane & 15;
  const bool isZ = (blockIdx.x < 1024);
  const int blk = isZ ? blockIdx.x : (blockIdx.x - 1024);
  const int b = blk >> 3;
  const int ch = (blk & 7) * 4 + g;
  const int len = lens[b];
#pragma unroll
  for (int pp = 0; pp < 4; ++pp) {
    int flat = pp * 64 + lane; int j = flat >> 4, i = flat & 15;
    float tv = trans[i * 16 + j];
    Wl[flat] = isZ ? __expf(tv) : tv;
  }
  const int t0 = 128 * (blk & 7) + 1;
#pragma unroll
  for (int pp = 0; pp < 8; ++pp) {
    int flat = pp * 64 + lane;              // float4 units
    int row = flat >> 2, q = flat & 3;
    int t = t0 + row; t = (t < 1023) ? t : 1023;
    float4 v4 = *(const float4*)(emis + ((size_t)t * B_ + b) * K_ + q * 4);
    if (isZ) { v4.x = __expf(v4.x); v4.y = __expf(v4.y); v4.z = __expf(v4.z); v4.w = __expf(v4.w); }
    *(float4*)&tile[row * 16 + q * 4] = v4;
  }
  __syncthreads();

  if (isZ) {
    float v[16];
#pragma unroll
    for (int i = 0; i < 16; ++i) v[i] = (i == c) ? 1.0f : 0.0f;
    float ell = 0.0f;
    for (int s = 0; s < CSZ; ++s) {
      const int t = ch * CSZ + 1 + s;
      const float* xr = &tile[(g * 32 + s) * 16];
      float4 x0 = *(const float4*)(xr), x1 = *(const float4*)(xr + 4),
             x2 = *(const float4*)(xr + 8), x3 = *(const float4*)(xr + 12);
      float xs[16] = {x0.x, x0.y, x0.z, x0.w, x1.x, x1.y, x1.z, x1.w,
                      x2.x, x2.y, x2.z, x2.w, x3.x, x3.y, x3.z, x3.w};
      float nv[16];
#pragma unroll
      for (int j = 0; j < 16; ++j) {
        const float* wr = &Wl[j * 16];
        float4 w0 = *(const float4*)(wr), w1 = *(const float4*)(wr + 4),
               w2 = *(const float4*)(wr + 8), w3 = *(const float4*)(wr + 12);
        float a;
        a = v[0] * w0.x;        a = fmaf(v[1], w0.y, a); a = fmaf(v[2], w0.z, a); a = fmaf(v[3], w0.w, a);
        a = fmaf(v[4], w1.x, a); a = fmaf(v[5], w1.y, a); a = fmaf(v[6], w1.z, a); a = fmaf(v[7], w1.w, a);
        a = fmaf(v[8], w2.x, a); a = fmaf(v[9], w2.y, a); a = fmaf(v[10], w2.z, a); a = fmaf(v[11], w2.w, a);
        a = fmaf(v[12], w3.x, a); a = fmaf(v[13], w3.y, a); a = fmaf(v[14], w3.z, a); a = fmaf(v[15], w3.w, a);
        nv[j] = a * xs[j];
      }
      const bool keep = (t < len);
#pragma unroll
      for (int j = 0; j < 16; ++j) v[j] = keep ? nv[j] : v[j];
      if ((s & 3) == 3) {                  // normalize every 4 steps; growth <= ~e^7/step
        float S = (((v[0] + v[1]) + (v[2] + v[3])) + ((v[4] + v[5]) + (v[6] + v[7]))) +
                  (((v[8] + v[9]) + (v[10] + v[11])) + ((v[12] + v[13]) + (v[14] + v[15])));
        float inv = __fdividef(1.0f, S);
        ell += __logf(S);
#pragma unroll
        for (int j = 0; j < 16; ++j) v[j] *= inv;
      }
    }
    float* dst = Mz + (size_t)(b * NCH + ch) * 256 + c;   // [ch][j][c]
#pragma unroll
    for (int j = 0; j < 16; ++j) dst[j * 16] = v[j];
    Lz[(b * NCH + ch) * 16 + c] = ell;
  } else {
    float v[16];
#pragma unroll
    for (int i = 0; i < 16; ++i) v[i] = (i == c) ? 0.0f : -1e30f;
    for (int s = 0; s < CSZ; ++s) {
      const int t = ch * CSZ + 1 + s;
      const float* xr = &tile[(g * 32 + s) * 16];
      float4 x0 = *(const float4*)(xr), x1 = *(const float4*)(xr + 4),
             x2 = *(const float4*)(xr + 8), x3 = *(const float4*)(xr + 12);
      float es[16] = {x0.x, x0.y, x0.z, x0.w, x1.x, x1.y, x1.z, x1.w,
                      x2.x, x2.y, x2.z, x2.w, x3.x, x3.y, x3.z, x3.w};
      float nv[16];
#pragma unroll
      for (int j = 0; j < 16; ++j) {
        const float* wr = &Wl[j * 16];
        float4 w0 = *(const float4*)(wr), w1 = *(const float4*)(wr + 4),
               w2 = *(const float4*)(wr + 8), w3 = *(const float4*)(wr + 12);
        float a0 = v[0] + w0.x,  a1 = v[1] + w0.y,  a2 = v[2] + w0.z,  a3 = v[3] + w0.w;
        float a4 = v[4] + w1.x,  a5 = v[5] + w1.y,  a6 = v[6] + w1.z,  a7 = v[7] + w1.w;
        float a8 = v[8] + w2.x,  a9 = v[9] + w2.y,  a10 = v[10] + w2.z, a11 = v[11] + w2.w;
        float a12 = v[12] + w3.x, a13 = v[13] + w3.y, a14 = v[14] + w3.z, a15 = v[15] + w3.w;
        float m = fmaxf(fmaxf(fmaxf(fmaxf(a0, a1), fmaxf(a2, a3)), fmaxf(fmaxf(a4, a5), fmaxf(a6, a7))),
                        fmaxf(fmaxf(fmaxf(a8, a9), fmaxf(a10, a11)), fmaxf(fmaxf(a12, a13), fmaxf(a14, a15))));
        nv[j] = m + es[j];
      }
      const bool keep = (t < len);
#pragma unroll
      for (int j = 0; j < 16; ++j) v[j] = keep ? nv[j] : v[j];
    }
    float* dst = Mv + (size_t)(b * NCH + ch) * 256 + c;   // [ch][j][c]
#pragma unroll
    for (int j = 0; j < 16; ++j) dst[j * 16] = v[j];
  }
}

// ---------- phase 2: blocks [0,32) logZ combine; [32,64) viterbi combine+boundary bt; [64,128) numerator ----------
// Transposed M layout -> lane l holds COLUMN l; combines are lane-local after one allgather level.
__global__ __launch_bounds__(64) void phase2_kernel(const float* __restrict__ emis,
                                                    const float* __restrict__ trans,
                                                    const float* __restrict__ start,
                                                    const float* __restrict__ endv,
                                                    const int* __restrict__ labels,
                                                    const int* __restrict__ lens,
                                                    const float* __restrict__ Mz,
                                                    const float* __restrict__ Lz,
                                                    const float* __restrict__ Mv,
                                                    float* __restrict__ logZ,
                                                    int* __restrict__ states,
                                                    float* __restrict__ num) {
  __shared__ unsigned char Bh[4][NCH][16];
  const int lane = threadIdx.x;

  if (blockIdx.x < 32) {
    // ---- logZ combine: p_next[l] = sum_c p[c] e^{ell_c - me} Mz[c][l]; double-buffered loads ----
    const int g = lane >> 4, l = lane & 15;
    const int b = blockIdx.x * 4 + g;
    const float* MT = Mz + (size_t)b * NCH * 256 + l * 16;   // + ch*256 + c
    const float* Lb = Lz + b * NCH * 16 + l;                 // + ch*16
    float pc = __expf(start[l] + emis[b * K_ + l]);          // t=0 (unmasked)
    float S0 = pc; SUM16(S0);
    float L = __logf(S0);
    pc = __fdividef(pc, S0);
    float4 c0 = *(const float4*)(MT + 0), c1 = *(const float4*)(MT + 4),
           c2 = *(const float4*)(MT + 8), c3 = *(const float4*)(MT + 12);
    float ellc = Lb[0];
    for (int ch = 0; ch < NCH; ++ch) {
      const int chn = (ch + 1 < NCH) ? (ch + 1) : (NCH - 1);
      const float* MTn = MT + (size_t)chn * 256;
      float4 n0 = *(const float4*)(MTn + 0), n1 = *(const float4*)(MTn + 4),
             n2 = *(const float4*)(MTn + 8), n3 = *(const float4*)(MTn + 12);
      float elln = Lb[chn * 16];
      float me = ellc;
      me = fmaxf(me, xshf16<1>(me)); me = fmaxf(me, xshf16<2>(me));
      me = fmaxf(me, xshf16<4>(me)); me = fmaxf(me, xshf16<8>(me));
      float w = pc * __expf(ellc - me);
      float wv[16];
      ALLGATHER16(wv, w);
      float pn;
      pn = wv[0] * c0.x;          pn = fmaf(wv[1], c0.y, pn);  pn = fmaf(wv[2], c0.z, pn);  pn = fmaf(wv[3], c0.w, pn);
      pn = fmaf(wv[4], c1.x, pn);  pn = fmaf(wv[5], c1.y, pn);  pn = fmaf(wv[6], c1.z, pn);  pn = fmaf(wv[7], c1.w, pn);
      pn = fmaf(wv[8], c2.x, pn);  pn = fmaf(wv[9], c2.y, pn);  pn = fmaf(wv[10], c2.z, pn); pn = fmaf(wv[11], c2.w, pn);
      pn = fmaf(wv[12], c3.x, pn); pn = fmaf(wv[13], c3.y, pn); pn = fmaf(wv[14], c3.z, pn); pn = fmaf(wv[15], c3.w, pn);
      float S = pn; SUM16(S);
      L += me + __logf(S);
      pc = __fdividef(pn, S);
      c0 = n0; c1 = n1; c2 = n2; c3 = n3; ellc = elln;
    }
    float u = pc * __expf(endv[l]);
    SUM16(u);
    if (l == 0) logZ[b] = L + __logf(u);

  } else if (blockIdx.x < 64) {
    // ---- Viterbi combine: lane-local argmax over sources; per-chunk backpointer bytes in LDS ----
    const int g = lane >> 4, l = lane & 15;
    const int b = (blockIdx.x - 32) * 4 + g;
    const float* MT = Mv + (size_t)b * NCH * 256 + l * 16;
    float gc = start[l] + emis[b * K_ + l];
    float4 c0 = *(const float4*)(MT + 0), c1 = *(const float4*)(MT + 4),
           c2 = *(const float4*)(MT + 8), c3 = *(const float4*)(MT + 12);
    for (int ch = 0; ch < NCH; ++ch) {
      const int chn = (ch + 1 < NCH) ? (ch + 1) : (NCH - 1);
      const float* MTn = MT + (size_t)chn * 256;
      float4 n0 = *(const float4*)(MTn + 0), n1 = *(const float4*)(MTn + 4),
             n2 = *(const float4*)(MTn + 8), n3 = *(const float4*)(MTn + 12);
      float gv[16];
      ALLGATHER16(gv, gc);
      float tv[16] = {gv[0] + c0.x,  gv[1] + c0.y,  gv[2] + c0.z,  gv[3] + c0.w,
                      gv[4] + c1.x,  gv[5] + c1.y,  gv[6] + c1.z,  gv[7] + c1.w,
                      gv[8] + c2.x,  gv[9] + c2.y,  gv[10] + c2.z, gv[11] + c2.w,
                      gv[12] + c3.x, gv[13] + c3.y, gv[14] + c3.z, gv[15] + c3.w};
      int ti[16];
#pragma unroll
      for (int i = 0; i < 16; ++i) ti[i] = i;
#pragma unroll
      for (int st = 8; st >= 1; st >>= 1) {   // tournament, LOWER source index wins ties
#pragma unroll
        for (int i = 0; i < st; ++i) {
          bool cgt = tv[i + st] > tv[i];
          tv[i] = cgt ? tv[i + st] : tv[i];
          ti[i] = cgt ? ti[i + st] : ti[i];
        }
      }
      Bh[g][ch][l] = (unsigned char)ti[0];
      gc = tv[0];
      c0 = n0; c1 = n1; c2 = n2; c3 = n3;
    }
    // final argmax over states (lowest index wins), converges across the 16-group
    float v = gc + endv[l];
    int idx = l;
    { float ov = xshf16<1>(v); int oi = xshf16i<1>(idx); bool tk = (ov > v) || ((ov == v) && (oi < idx)); v = tk ? ov : v; idx = tk ? oi : idx; }
    { float ov = xshf16<2>(v); int oi = xshf16i<2>(idx); bool tk = (ov > v) || ((ov == v) && (oi < idx)); v = tk ? ov : v; idx = tk ? oi : idx; }
    { float ov = xshf16<4>(v); int oi = xshf16i<4>(idx); bool tk = (ov > v) || ((ov == v) && (oi < idx)); v = tk ? ov : v; idx = tk ? oi : idx; }
    { float ov = xshf16<8>(v); int oi = xshf16i<8>(idx); bool tk = (ov > v) || ((ov == v) && (oi < idx)); v = tk ? ov : v; idx = tk ? oi : idx; }
    int sc = idx;
    if (l == 0) states[b * (NCH + 1) + NCH] = sc;
    for (int ch = NCH - 1; ch >= 0; --ch) {
      sc = Bh[g][ch][sc];                   // uniform within group -> LDS broadcast
      if (l == 0) states[b * (NCH + 1) + ch] = sc;
    }

  } else {
    // ---- numerator: 2 batches/block, lane owns 32 consecutive t's -> 32 gathers in flight ----
    const int l5 = lane & 31;
    const int b = (blockIdx.x - 64) * 2 + (lane >> 5);
    const int len = lens[b];
    const int* lab = labels + b * T_;
    const int t0 = l5 * 32;
    int prev = (l5 > 0) ? lab[t0 - 1] : 0;
    float acc = 0.0f;
#pragma unroll
    for (int i = 0; i < 32; ++i) {
      const int t = t0 + i;
      int lt = lab[t];
      float e = emis[((size_t)t * B_ + b) * K_ + lt];
      float tr = trans[prev * K_ + lt];
      float term = (t == 0) ? (start[lt] + e) : ((t < len) ? (tr + e) : 0.0f);
      acc += term;
      prev = lt;
    }
    SUM32(acc);
    if (l5 == 0) num[b] = acc + endv[lab[len - 1]];
  }
}

// ---------- phase 3: re-run each viterbi chunk from known entry state; backtrack in-chunk; block 0 adds loss ----------
__global__ __launch_bounds__(64) void phase3_kernel(const float* __restrict__ emis,
                                                    const float* __restrict__ trans,
                                                    const int* __restrict__ lens,
                                                    const int* __restrict__ states,
                                                    const float* __restrict__ num,
                                                    const float* __restrict__ logZ,
                                                    float* __restrict__ out) {
  __shared__ float tile[128 * 16];               // raw e rows, 8 KB
  __shared__ unsigned char hist_lds[CSZ * 64];   // [s][lane], 2 KB
  const int lane = threadIdx.x;
  const int g = lane >> 4, j = lane & 15;
  const int blk = blockIdx.x;
  const int b = blk >> 3;
  const int ch = (blk & 7) * 4 + g;
  const int len = lens[b];
  const int t0 = 128 * (blk & 7) + 1;
#pragma unroll
  for (int pp = 0; pp < 8; ++pp) {
    int flat = pp * 64 + lane;
    int row = flat >> 2, q = flat & 3;
    int t = t0 + row; t = (t < 1023) ? t : 1023;
    *(float4*)&tile[row * 16 + q * 4] = *(const float4*)(emis + ((size_t)t * B_ + b) * K_ + q * 4);
  }
  __syncthreads();
  const int s_in  = states[b * (NCH + 1) + ch];
  const int s_out = states[b * (NCH + 1) + ch + 1];
  float Tc[16];
#pragma unroll
  for (int i = 0; i < 16; ++i) Tc[i] = trans[i * K_ + j];   // column j
  float sc = (j == s_in) ? 0.0f : -1e30f;
  for (int s = 0; s < CSZ; ++s) {
    const int t = ch * CSZ + 1 + s;
    float e = tile[(g * 32 + s) * 16 + j];
    float sv[16];
    ALLGATHER16(sv, sc);
    float tv[16]; int ti[16];
#pragma unroll
    for (int i = 0; i < 16; ++i) { tv[i] = sv[i] + Tc[i]; ti[i] = i; }
#pragma unroll
    for (int st = 8; st >= 1; st >>= 1) {
#pragma unroll
      for (int i = 0; i < st; ++i) {
        bool cgt = tv[i + st] > tv[i];
        tv[i] = cgt ? tv[i + st] : tv[i];
        ti[i] = cgt ? ti[i + st] : ti[i];
      }
    }
    hist_lds[s * 64 + lane] = (unsigned char)ti[0];
    float nxt = tv[0] + e;
    sc = (t < len) ? nxt : sc;    // t>=1024 (ch=31,s=31) always masked since len<=1024
  }
  // backtrack within chunk from exit state
  int cur = s_out;
  for (int s = CSZ - 1; s >= 0; --s) {
    const int t = ch * CSZ + 1 + s;
    if (t < T_) {
      bool m = (t < len);
      if (j == 0) out[b * T_ + t] = m ? (float)cur : 0.0f;   // tag BEFORE stepping
      int h = hist_lds[s * 64 + lane];
      int prev = __shfl(h, (lane & 48) | cur);
      cur = m ? prev : cur;
    }
  }
  if (ch == 0 && j == 0) out[b * T_] = (float)cur;
  // ---- fused loss: block 0 reduces -mean(num - logZ) ----
  if (blk == 0) {
    float s = (num[lane] - logZ[lane]) + (num[lane + 64] - logZ[lane + 64]);
#pragma unroll
    for (int m = 1; m < 64; m <<= 1) s += __shfl_xor(s, m);
    if (lane == 0) out[B_ * T_] = -s / (float)B_;
  }
}

extern "C" void kernel_launch(void* const* d_in, const int* in_sizes, int n_in,
                              void* d_out, int out_size, void* d_ws, size_t ws_size,
                              hipStream_t stream) {
  const float* H      = (const float*)d_in[0];
  const void*  maskp  = d_in[1];
  const int*   labels = (const int*)d_in[2];
  const float* W      = (const float*)d_in[3];
  const float* bias   = (const float*)d_in[4];
  const float* start  = (const float*)d_in[5];
  const float* trans  = (const float*)d_in[6];
  const float* endv   = (const float*)d_in[7];

  char* ws = (char*)d_ws;
  float* emis  = (float*)ws;                         //  8 MB   emis[t][b][k]
  float* Mz    = (float*)(ws + 8388608);             //  4 MB   [b][ch][j][c] (transposed)
  float* Lz    = (float*)(ws + 12582912);            //  256 KB [b][ch][c]
  float* Mv    = (float*)(ws + 12845056);            //  4 MB   [b][ch][j][c] (transposed)
  int*   states= (int*)  (ws + 17039360);            //  17 KB  [b][33]
  float* num   = (float*)(ws + 17056256);            //  512 B
  float* logZ  = (float*)(ws + 17056768);            //  512 B
  int*   lens  = (int*)  (ws + 17057280);            //  512 B
  float* out   = (float*)d_out;

  emis_kernel<<<dim3((B_ * T_) / 256), dim3(256), 0, stream>>>(H, W, bias, maskp, emis, lens);
  phase1_kernel<<<dim3(2048), dim3(64), 0, stream>>>(emis, trans, lens, Mz, Lz, Mv);
  phase2_kernel<<<dim3(128), dim3(64), 0, stream>>>(emis, trans, start, endv, labels, lens,
                                                    Mz, Lz, Mv, logZ, states, num);
  phase3_kernel<<<dim3(1024), dim3(64), 0, stream>>>(emis, trans, lens, states, num, logZ, out);
}